// Round 14
// baseline (224.740 us; speedup 1.0000x reference)
//
#include <hip/hip_runtime.h>
#include <hip/hip_bf16.h>
#include <math.h>

// B=64 N=1025 D=384 K=8 R=8 KS=8 H=128 CIN=1152 OUT=384 ; rank m = 2*K*R = 128
static const int Bb = 64, Nn = 1025, Dd = 384, Kk = 8, Rr = 8, Hh = 128, CINc = 1152, OUTo = 384;

// ---- workspace layout (float offsets) ----
#define OFF_PSTAT 0u
#define OFF_RC    475136u
#define OFF_RG    475648u
#define OFF_LG    475712u
#define OFF_SCALE 476288u
#define OFF_N2    505472u
#define OFF_P     505600u
#define OFF_Q     554752u
#define OFF_G     603904u
#define OFF_QW    620288u
#define OFF_PB    669440u
#define OFF_EP    694016u
#define OFF_ZT    3839744u
#define OFF_WBT   5412608u
#define OFF_LM    10131200u

typedef __attribute__((ext_vector_type(8))) short short8;
typedef __attribute__((ext_vector_type(8))) __bf16 bf16x8;
typedef __attribute__((ext_vector_type(4))) float f32x4;

#define MFMA_BF16(a,b,c) __builtin_amdgcn_mfma_f32_16x16x32_bf16( \
    __builtin_bit_cast(bf16x8,(a)), __builtin_bit_cast(bf16x8,(b)), (c), 0, 0, 0)

#define GLDS16(gp, lp) __builtin_amdgcn_global_load_lds( \
    (__attribute__((address_space(1))) void*)(gp), \
    (__attribute__((address_space(3))) void*)(lp), 16, 0, 0)

__device__ __forceinline__ float gelu_t(float v){
    float u = 0.7978845608028654f*(v + 0.044715f*v*v*v);
    return 0.5f*v*(1.0f + tanhf(u));
}
__device__ __forceinline__ float sigm(float v){ return 1.0f/(1.0f+expf(-v)); }
__device__ __forceinline__ unsigned short f2bf(float v){
    return __builtin_bit_cast(unsigned short, __float2bfloat16(v));
}

// ================= A: stats (0..511) | n2 (512..519) | P/Q (520..647) =================
__global__ __launch_bounds__(384) void k_statsprep(const float* __restrict__ x,
    const float* __restrict__ lb, const float* __restrict__ rb,
    float* __restrict__ ps, float* __restrict__ n2,
    float* __restrict__ P, float* __restrict__ Q, unsigned short* __restrict__ Pb){
    int bid = blockIdx.x, t = threadIdx.x;
    if (bid < 512){
        int s = bid & 7, b = bid >> 3;
        int dq = t % 96, ng = t / 96;
        int n0 = s*129, n1 = n0+129 < Nn ? n0+129 : Nn;
        const float4* xb = (const float4*)(x + (size_t)b*Nn*Dd);
        float4 sm = make_float4(0.f,0.f,0.f,0.f), sq = make_float4(0.f,0.f,0.f,0.f);
        for (int n = n0+ng; n < n1; n += 4){
            float4 v = xb[(size_t)n*96 + dq];
            sm.x += v.x; sm.y += v.y; sm.z += v.z; sm.w += v.w;
            sq.x += v.x*v.x; sq.y += v.y*v.y; sq.z += v.z*v.z; sq.w += v.w*v.w;
        }
        __shared__ float4 smS[384];
        __shared__ float4 sqS[384];
        smS[t] = sm; sqS[t] = sq;
        __syncthreads();
        if (t < 96){
            float4 a0 = smS[t], a1 = smS[t+96], a2 = smS[t+192], a3 = smS[t+288];
            float4 q0 = sqS[t], q1 = sqS[t+96], q2 = sqS[t+192], q3 = sqS[t+288];
            float4 a = make_float4(a0.x+a1.x+a2.x+a3.x, a0.y+a1.y+a2.y+a3.y, a0.z+a1.z+a2.z+a3.z, a0.w+a1.w+a2.w+a3.w);
            float4 q = make_float4(q0.x+q1.x+q2.x+q3.x, q0.y+q1.y+q2.y+q3.y, q0.z+q1.z+q2.z+q3.z, q0.w+q1.w+q2.w+q3.w);
            ((float4*)(ps + ((size_t)(b*8+s)*2+0)*Dd))[t] = a;
            ((float4*)(ps + ((size_t)(b*8+s)*2+1)*Dd))[t] = q;
        }
    } else if (bid < 520){
        if (t < 64){
            int k = bid - 512;
            int r = t >> 3, s2 = t & 7;
            const float* L = lb + (size_t)k*Dd*Rr;
            const float* R = rb + (size_t)k*Dd*Rr;
            float a = 0.f, bsum = 0.f, c = 0.f, c2 = 0.f;
            for (int d = 0; d < Dd; ++d){
                float lr = L[d*8+r], ls = L[d*8+s2], rr = R[d*8+r], rs = R[d*8+s2];
                a += lr*ls; bsum += rr*rs; c += lr*rs; c2 += ls*rr;
            }
            float contrib = a*bsum - c*c2;
            for (int m = 32; m > 0; m >>= 1) contrib += __shfl_xor(contrib, m, 64);
            if (t == 0) n2[k] = 2.f*contrib;
        }
    } else {
        int idx = (bid - 520)*384 + t;
        int d = idx >> 7, j = idx & 127;
        int k = (j & 63) >> 3, r = j & 7;
        float lv = lb[((size_t)k*Dd + d)*Rr + r];
        float rv = rb[((size_t)k*Dd + d)*Rr + r];
        float pv = (j < 64) ? lv : rv;
        P[idx] = pv;
        Pb[idx] = f2bf(pv);
        Q[idx] = (j < 64) ? rv : lv;
    }
}

// ================= B: gramqw (0..127) | ctrl (128..191) =================
__global__ __launch_bounds__(512) void k_ctrlgram(const float* __restrict__ x, const float* __restrict__ ps,
    const float* __restrict__ w1, const float* __restrict__ b1,
    const float* __restrict__ w_rot, const float* __restrict__ b_rot,
    const float* __restrict__ w_rg, const float* __restrict__ b_rg,
    const float* __restrict__ w_lg, const float* __restrict__ b_lg,
    const float* __restrict__ w_sc, const float* __restrict__ b_sc,
    const float* __restrict__ sbasis, const float* __restrict__ sstr,
    const float* __restrict__ P, const float* __restrict__ Q, const float* __restrict__ Wsh,
    float* __restrict__ rc, float* __restrict__ rg, float* __restrict__ lg,
    float* __restrict__ scalev, unsigned short* __restrict__ lm,
    float* __restrict__ G, float* __restrict__ QW){
    int bid = blockIdx.x, t = threadIdx.x;
    if (bid < 128){
        __shared__ float qc[384];
        int i = bid;
        for (int d = t; d < Dd; d += 512) qc[d] = Q[d*128 + i];
        __syncthreads();
        if (t < 128){
            float a = 0.f;
            for (int d = 0; d < Dd; ++d) a += qc[d]*P[d*128 + t];
            G[i*128 + t] = a;
        } else {
            int o = t - 128;
            float a = 0.f;
            const float* wrow = Wsh + (size_t)o*Dd;
            for (int d = 0; d < Dd; ++d) a += qc[d]*wrow[d];
            QW[(size_t)i*OUTo + o] = a;
        }
    } else {
        __shared__ float zs[1152];
        __shared__ float hp[4*128];
        __shared__ float hs[128];
        __shared__ float scl[8];
        int b = bid - 128;
        if (t < 384){
            float sm = 0.f, sq = 0.f;
            for (int s = 0; s < 8; ++s){
                sm += ps[((size_t)(b*8+s)*2+0)*Dd + t];
                sq += ps[((size_t)(b*8+s)*2+1)*Dd + t];
            }
            float mean = sm*(1.0f/Nn);
            float var  = sq*(1.0f/Nn) - mean*mean;
            float cls  = x[(size_t)b*Nn*Dd + t];
            zs[t] = cls; zs[Dd + t] = mean; zs[2*Dd + t] = var;
            lm[(size_t)b*Nn*Dd + t] = f2bf(cls);
        }
        __syncthreads();
        {
            int row = t & 127, part = t >> 7;
            const float* wrow = w1 + (size_t)row*CINc + part*288;
            const float* zp = zs + part*288;
            float acc = 0.f;
            for (int c = 0; c < 288; ++c) acc += zp[c]*wrow[c];
            hp[part*128 + row] = acc;
        }
        __syncthreads();
        if (t < 128)
            hs[t] = gelu_t(hp[t] + hp[128+t] + hp[256+t] + hp[384+t] + b1[t]);
        __syncthreads();
        if (t < 8){
            float acc = b_rot[t]; const float* w = w_rot + (size_t)t*Hh;
            for (int c = 0; c < Hh; ++c) acc += hs[c]*w[c];
            rc[b*8+t] = tanhf(acc);
        } else if (t == 8){
            float acc = b_rg[0];
            for (int c = 0; c < Hh; ++c) acc += hs[c]*w_rg[c];
            rg[b] = sigm(acc);
        } else if (t == 9){
            float acc = b_lg[0];
            for (int c = 0; c < Hh; ++c) acc += hs[c]*w_lg[c];
            lg[b] = sigm(acc);
        } else if (t < 18){
            int q = t-10; float acc = b_sc[q]; const float* w = w_sc + (size_t)q*Hh;
            for (int c = 0; c < Hh; ++c) acc += hs[c]*w[c];
            scl[q] = tanhf(acc);
        }
        __syncthreads();
        if (t < 384){
            float acc = 0.f;
            #pragma unroll
            for (int q = 0; q < 8; ++q) acc += scl[q]*sbasis[q*OUTo + t];
            scalev[(size_t)b*OUTo + t] = 1.0f + sstr[0]*tanhf(acc);
        }
    }
}

// ---- fused Cayley/Neumann: X = sum_{k<=2} (DG)^k B0, Ep = rg*(D + X) ----
__global__ __launch_bounds__(512) void k_cayley(const float* __restrict__ G, const float* __restrict__ rc,
                                                const float* __restrict__ n2, const float* __restrict__ rg,
                                                float* __restrict__ Ep){
    __shared__ float GT[128*128];
    __shared__ float Xs[128*128];
    int b = blockIdx.x, t = threadIdx.x;
    for (int lin = t; lin < 16384; lin += 512){
        int i = lin >> 7, m = lin & 127;
        GT[m*128 + i] = G[lin];
    }
    int j0 = (t & 15)*8, i0 = (t >> 4)*4;
    float dj[8], di[4];
    #pragma unroll
    for (int u = 0; u < 8; ++u){
        int j = j0+u; int k = (j&63)>>3;
        float nrm = fmaxf(sqrtf(n2[k]), 1e-6f);
        float al = 0.5f*rc[b*8+k]/nrm;
        dj[u] = (j < 64) ? al : -al;
    }
    #pragma unroll
    for (int u = 0; u < 4; ++u){
        int i = i0+u; int k = (i&63)>>3;
        float nrm = fmaxf(sqrtf(n2[k]), 1e-6f);
        float al = 0.5f*rc[b*8+k]/nrm;
        di[u] = (i < 64) ? al : -al;
    }
    __syncthreads();
    float B0[4][8], acc[4][8];
    #pragma unroll
    for (int ui = 0; ui < 4; ++ui)
        #pragma unroll
        for (int uj = 0; uj < 8; ++uj){
            int i = i0+ui, j = j0+uj;
            float g = GT[j*128 + i];
            B0[ui][uj] = di[ui]*g*dj[uj] + ((i==j) ? di[ui] : 0.f);
        }
    #pragma unroll
    for (int ui = 0; ui < 4; ++ui)
        #pragma unroll
        for (int uj = 0; uj < 8; ++uj)
            Xs[(i0+ui)*128 + j0+uj] = B0[ui][uj];
    __syncthreads();
    for (int pass = 0; pass < 2; ++pass){
        #pragma unroll
        for (int ui = 0; ui < 4; ++ui)
            #pragma unroll
            for (int uj = 0; uj < 8; ++uj) acc[ui][uj] = 0.f;
        for (int m = 0; m < 128; ++m){
            float4 g4 = *(const float4*)&GT[m*128 + i0];
            float4 xa = *(const float4*)&Xs[m*128 + j0];
            float4 xb = *(const float4*)&Xs[m*128 + j0 + 4];
            float gi[4] = {g4.x, g4.y, g4.z, g4.w};
            float xv[8] = {xa.x, xa.y, xa.z, xa.w, xb.x, xb.y, xb.z, xb.w};
            #pragma unroll
            for (int ui = 0; ui < 4; ++ui)
                #pragma unroll
                for (int uj = 0; uj < 8; ++uj)
                    acc[ui][uj] += gi[ui]*xv[uj];
        }
        if (pass == 0){
            __syncthreads();
            #pragma unroll
            for (int ui = 0; ui < 4; ++ui)
                #pragma unroll
                for (int uj = 0; uj < 8; ++uj)
                    Xs[(i0+ui)*128 + j0+uj] = B0[ui][uj] + di[ui]*acc[ui][uj];
            __syncthreads();
        }
    }
    float rgb = rg[b];
    #pragma unroll
    for (int ui = 0; ui < 4; ++ui){
        int i = i0+ui;
        float o[8];
        #pragma unroll
        for (int uj = 0; uj < 8; ++uj){
            int j = j0+uj;
            float x2 = B0[ui][uj] + di[ui]*acc[ui][uj];
            o[uj] = rgb*(x2 + ((i==j) ? di[ui] : 0.f));
        }
        float4* ep4 = (float4*)(Ep + ((size_t)b*128 + i)*128 + j0);
        ep4[0] = make_float4(o[0], o[1], o[2], o[3]);
        ep4[1] = make_float4(o[4], o[5], o[6], o[7]);
    }
}

// ================= D: lm sliding-window (0..2047) | zmatT (2048..4095) =================
__global__ __launch_bounds__(384) void k_zmlm(const float* __restrict__ x, const float* __restrict__ kw,
    const float* __restrict__ lg, const float* __restrict__ Ep, const float* __restrict__ QW,
    unsigned short* __restrict__ lm, unsigned short* __restrict__ ZT){
    __shared__ float shf[3456];
    int bid = blockIdx.x, t = threadIdx.x;
    if (bid < 2048){
        int work = (bid & 7)*256 + (bid >> 3);
        int b = work >> 5, gy = work & 31;
        for (int i = t; i < 3456; i += 384){
            int d = i % 384, tap = i / 384;
            shf[tap*384 + d] = kw[d*9 + tap];
        }
        __syncthreads();
        int dq = t % 96, gxg = t / 96;
        int gx0 = gxg*8;
        float4 kvr[9];
        #pragma unroll
        for (int tap = 0; tap < 9; ++tap)
            kvr[tap] = *(const float4*)(&shf[tap*384 + dq*4]);
        float lgb = lg[b];
        const float4* xb = (const float4*)(x + (size_t)b*Nn*Dd);
        unsigned short* lmb = lm + (size_t)b*Nn*Dd;
        float4 zero4 = make_float4(0.f,0.f,0.f,0.f);
        bool rv[3]; int coff[3];
        #pragma unroll
        for (int rr2 = 0; rr2 < 3; ++rr2){
            int yy = gy + rr2 - 1;
            rv[rr2] = (unsigned)yy < 32u;
            coff[rr2] = (1 + (yy << 5))*96 + dq;   // 32-bit f4-offset of col 0
        }
        float4 win[3][3];
        #pragma unroll
        for (int rr2 = 0; rr2 < 3; ++rr2){
            win[rr2][0] = (rv[rr2] && gx0 > 0) ? xb[coff[rr2] + (gx0-1)*96] : zero4;
            win[rr2][1] = rv[rr2] ? xb[coff[rr2] + gx0*96] : zero4;
            coff[rr2] += (gx0+1)*96;               // col gx0+1 (u=0's load)
        }
        #pragma unroll
        for (int u = 0; u < 8; ++u){
            if (u < 7){
                #pragma unroll
                for (int rr2 = 0; rr2 < 3; ++rr2)
                    win[rr2][2] = rv[rr2] ? xb[coff[rr2]] : zero4;
            } else {
                #pragma unroll
                for (int rr2 = 0; rr2 < 3; ++rr2)
                    win[rr2][2] = (rv[rr2] && gxg < 3) ? xb[coff[rr2]] : zero4;
            }
            float ax = 0.f, ay = 0.f, az = 0.f, aw = 0.f;
            #pragma unroll
            for (int rr2 = 0; rr2 < 3; ++rr2)
                #pragma unroll
                for (int cc = 0; cc < 3; ++cc){
                    float4 xv = win[rr2][cc];
                    float4 kv = kvr[rr2*3+cc];
                    ax += xv.x*kv.x; ay += xv.y*kv.y; az += xv.z*kv.z; aw += xv.w*kv.w;
                }
            float4 xc = win[1][1];
            int gx = gx0 + u;
            int n = 1 + (gy << 5) + gx;
            ushort4 o4;
            o4.x = f2bf(xc.x + lgb*(ax - xc.x));
            o4.y = f2bf(xc.y + lgb*(ay - xc.y));
            o4.z = f2bf(xc.z + lgb*(az - xc.z));
            o4.w = f2bf(xc.w + lgb*(aw - xc.w));
            *(ushort4*)(lmb + (size_t)n*Dd + dq*4) = o4;
            #pragma unroll
            for (int rr2 = 0; rr2 < 3; ++rr2){
                win[rr2][0] = win[rr2][1];
                win[rr2][1] = win[rr2][2];
                coff[rr2] += 96;
            }
        }
    } else {
        float* Es = shf;
        int z = bid - 2048;
        int ig = z & 31, b = z >> 5;
        int i0 = ig*4;
        for (int lin = t; lin < 512; lin += 384)
            Es[lin] = Ep[((size_t)b*128 + i0 + (lin >> 7))*128 + (lin & 127)];
        __syncthreads();
        float a0=0.f, a1=0.f, a2=0.f, a3=0.f;
        for (int m = 0; m < 128; ++m){
            float qw = QW[(size_t)m*OUTo + t];
            a0 += Es[m]*qw; a1 += Es[128+m]*qw; a2 += Es[256+m]*qw; a3 += Es[384+m]*qw;
        }
        ushort4 uv;
        uv.x = f2bf(a0); uv.y = f2bf(a1); uv.z = f2bf(a2); uv.w = f2bf(a3);
        *(ushort4*)(ZT + ((size_t)b*OUTo + t)*128 + i0) = uv;
    }
}

// ---- WbT[b][o][d] = Wsh[o][d] + sum_m ZT[b][o][m]*P[d][m] (MFMA NT, bf16 out) ----
__global__ __launch_bounds__(256) void k_wbt(const unsigned short* __restrict__ ZT, const unsigned short* __restrict__ Pb,
                                             const float* __restrict__ Wsh, unsigned short* __restrict__ WbT){
    __shared__ short8 As[256];
    __shared__ short8 Bs[256];
    int b = blockIdx.y;
    int mt = blockIdx.x/6, nt2 = blockIdx.x%6;
    int m0 = mt*64, n0 = nt2*64;
    int t = threadIdx.x;
    int w = t>>6, l = t&63;
    int wr = w>>1, wc = w&1;
    const unsigned short* Ab = ZT + (size_t)b*OUTo*128;
    int lrow = t>>2, lseg = t&3;
    f32x4 acc[2][2];
    #pragma unroll
    for (int mi=0;mi<2;++mi)
        #pragma unroll
        for (int ni=0;ni<2;++ni)
            #pragma unroll
            for (int q=0;q<4;++q) acc[mi][ni][q] = 0.f;
    for (int kt = 0; kt < 4; ++kt){
        int k0 = kt*32;
        short8 av = *(const short8*)(Ab + (size_t)(m0+lrow)*128 + k0 + lseg*8);
        short8 bv = *(const short8*)(Pb + (size_t)(n0+lrow)*128 + k0 + lseg*8);
        __syncthreads();
        As[lseg*64 + lrow] = av;
        Bs[lseg*64 + lrow] = bv;
        __syncthreads();
        short8 a0 = As[(l>>4)*64 + wr*32 + (l&15)];
        short8 a1 = As[(l>>4)*64 + wr*32 + 16 + (l&15)];
        short8 b0 = Bs[(l>>4)*64 + wc*32 + (l&15)];
        short8 b1 = Bs[(l>>4)*64 + wc*32 + 16 + (l&15)];
        acc[0][0] = MFMA_BF16(a0, b0, acc[0][0]);
        acc[0][1] = MFMA_BF16(a0, b1, acc[0][1]);
        acc[1][0] = MFMA_BF16(a1, b0, acc[1][0]);
        acc[1][1] = MFMA_BF16(a1, b1, acc[1][1]);
    }
    unsigned short* Wo = WbT + (size_t)b*OUTo*Dd;
    #pragma unroll
    for (int mi=0;mi<2;++mi){
        #pragma unroll
        for (int ni=0;ni<2;++ni){
            int col = n0 + wc*32 + ni*16 + (l&15);
            #pragma unroll
            for (int r=0;r<4;++r){
                int row = m0 + wr*32 + mi*16 + (l>>4)*4 + r;
                float v = Wsh[(size_t)row*Dd + col] + acc[mi][ni][r];
                Wo[(size_t)row*Dd + col] = f2bf(v);
            }
        }
    }
}

// ---- out = (lm_bf16 @ Wb + bias)*scale ; 128x128, BK=32, 4-buf single-barrier depth-2 (R12-proven) ----
__global__ __launch_bounds__(256) void k_gemm_nt(const unsigned short* __restrict__ lm, const unsigned short* __restrict__ WbT,
                                                 const float* __restrict__ bias, const float* __restrict__ scalev,
                                                 float* __restrict__ out){
    __shared__ unsigned short smem[32768];   // 64 KB: 4 bufs x (A 4096 us | B 4096 us)
    __shared__ float svs[128];
    __shared__ float bvs[128];
    int flat = blockIdx.x;                      // 1728
    int work = (flat & 7)*216 + (flat >> 3);    // XCD-chunked (1728 % 8 == 0, bijective)
    int b = work / 27;
    int r = work - b*27;
    int nt = r / 3, ot = r - nt*3;
    int n0 = nt*128, o0 = ot*128;
    int t = threadIdx.x;
    int w = t >> 6, l = t & 63;
    int wr = w >> 1, wc = w & 1;
    const unsigned short* Ab = lm + (size_t)b*Nn*Dd;
    const unsigned short* Bt = WbT + (size_t)b*OUTo*Dd;
    if (t < 128){ svs[t] = scalev[(size_t)b*OUTo + o0 + t]; bvs[t] = bias[o0 + t]; }
    int srow = l >> 2;
    int gch  = (l & 3) ^ ((l >> 3) & 3);
    f32x4 acc[4][4];
    #pragma unroll
    for (int fi = 0; fi < 4; ++fi)
        #pragma unroll
        for (int fj = 0; fj < 4; ++fj)
            #pragma unroll
            for (int q = 0; q < 4; ++q) acc[fi][fj][q] = 0.f;

#define STG(bufi, k0) { \
    unsigned short* Adst = &smem[(bufi)*8192 + (w*32)*32]; \
    unsigned short* Bdst = &smem[(bufi)*8192 + 4096 + (w*32)*32]; \
    GLDS16(Ab + (size_t)(n0 + w*32 + srow)*Dd + (k0) + gch*8, Adst); \
    GLDS16(Ab + (size_t)(n0 + w*32 + 16 + srow)*Dd + (k0) + gch*8, Adst + 512); \
    GLDS16(Bt + (size_t)(o0 + w*32 + srow)*Dd + (k0) + gch*8, Bdst); \
    GLDS16(Bt + (size_t)(o0 + w*32 + 16 + srow)*Dd + (k0) + gch*8, Bdst + 512); }

    STG(0, 0);
    STG(1, 32);
    int rch = ((l>>4) ^ (((l&15)>>1)&3)) * 8;
    int raBase = (wr*64 + (l&15))*32;
    int rbBase = (wc*64 + (l&15))*32;
    for (int kt = 0; kt < 12; ++kt){
        if (kt < 10) STG((kt+2)&3, (kt+2)*32);
        if (kt < 10)       asm volatile("s_waitcnt vmcnt(8)" ::: "memory");
        else if (kt == 10) asm volatile("s_waitcnt vmcnt(4)" ::: "memory");
        else               asm volatile("s_waitcnt vmcnt(0)" ::: "memory");
        __builtin_amdgcn_s_barrier();        // AFTER own-vmcnt: cross-wave staged data visible
        __builtin_amdgcn_sched_barrier(0);
        const unsigned short* As  = &smem[(kt&3)*8192];
        const unsigned short* Bs2 = &smem[(kt&3)*8192 + 4096];
        short8 a[4], bb[4];
        #pragma unroll
        for (int f = 0; f < 4; ++f){
            a[f]  = *(const short8*)&As [raBase + f*512 + rch];
            bb[f] = *(const short8*)&Bs2[rbBase + f*512 + rch];
        }
        #pragma unroll
        for (int fi = 0; fi < 4; ++fi)
            #pragma unroll
            for (int fj = 0; fj < 4; ++fj)
                acc[fi][fj] = MFMA_BF16(a[fi], bb[fj], acc[fi][fj]);
        // no trailing barrier: next STG targets (kt+3)&3 — not read by any skew-1 wave
    }
#undef STG
    float* Cs = (float*)smem;            // [64][132] f32
    #pragma unroll
    for (int h = 0; h < 2; ++h){
        __syncthreads();
        if (wr == h){
            #pragma unroll
            for (int fi = 0; fi < 4; ++fi)
                #pragma unroll
                for (int fj = 0; fj < 4; ++fj){
                    int col = wc*64 + fj*16 + (l&15);
                    #pragma unroll
                    for (int q = 0; q < 4; ++q){
                        int row = fi*16 + (l>>4)*4 + q;
                        Cs[row*132 + col] = acc[fi][fj][q];
                    }
                }
        }
        __syncthreads();
        #pragma unroll
        for (int p = 0; p < 8; ++p){
            int idx = p*256 + t;
            int row = idx >> 5, c4 = idx & 31;
            int gr = n0 + h*64 + row;
            if (gr < Nn){
                float4 v = *(const float4*)&Cs[row*132 + c4*4];
                float4 o4;
                o4.x = svs[c4*4+0]*(bvs[c4*4+0] + v.x);
                o4.y = svs[c4*4+1]*(bvs[c4*4+1] + v.y);
                o4.z = svs[c4*4+2]*(bvs[c4*4+2] + v.z);
                o4.w = svs[c4*4+3]*(bvs[c4*4+3] + v.w);
                *(float4*)(out + ((size_t)b*Nn + gr)*OUTo + o0 + c4*4) = o4;
            }
        }
    }
}

extern "C" void kernel_launch(void* const* d_in, const int* in_sizes, int n_in,
                              void* d_out, int out_size, void* d_ws, size_t ws_size,
                              hipStream_t stream){
    const float* x     = (const float*)d_in[0];
    const float* Wsh   = (const float*)d_in[1];
    const float* bias  = (const float*)d_in[2];
    const float* lb    = (const float*)d_in[3];
    const float* rb    = (const float*)d_in[4];
    const float* sbasis= (const float*)d_in[5];
    const float* sstr  = (const float*)d_in[6];
    const float* kw    = (const float*)d_in[7];
    const float* w1    = (const float*)d_in[8];
    const float* b1    = (const float*)d_in[9];
    const float* w_rot = (const float*)d_in[10];
    const float* b_rot = (const float*)d_in[11];
    const float* w_rg  = (const float*)d_in[12];
    const float* b_rg  = (const float*)d_in[13];
    const float* w_lg  = (const float*)d_in[14];
    const float* b_lg  = (const float*)d_in[15];
    const float* w_sc  = (const float*)d_in[16];
    const float* b_sc  = (const float*)d_in[17];
    float* out = (float*)d_out;
    float* ws  = (float*)d_ws;

    float* ps     = ws + OFF_PSTAT;
    float* rc     = ws + OFF_RC;
    float* rg     = ws + OFF_RG;
    float* lg     = ws + OFF_LG;
    float* scalev = ws + OFF_SCALE;
    float* n2     = ws + OFF_N2;
    float* P      = ws + OFF_P;
    float* Q      = ws + OFF_Q;
    float* G      = ws + OFF_G;
    float* QW     = ws + OFF_QW;
    unsigned short* Pb  = (unsigned short*)(ws + OFF_PB);
    float* Ep     = ws + OFF_EP;
    unsigned short* ZT  = (unsigned short*)(ws + OFF_ZT);
    unsigned short* WbT = (unsigned short*)(ws + OFF_WBT);
    unsigned short* lmb = (unsigned short*)(ws + OFF_LM);

    k_statsprep<<<648, 384, 0, stream>>>(x, lb, rb, ps, n2, P, Q, Pb);
    k_ctrlgram <<<192, 512, 0, stream>>>(x, ps, w1, b1, w_rot, b_rot, w_rg, b_rg, w_lg, b_lg,
                                         w_sc, b_sc, sbasis, sstr, P, Q, Wsh,
                                         rc, rg, lg, scalev, lmb, G, QW);
    k_cayley   <<<Bb, 512, 0, stream>>>(G, rc, n2, rg, Ep);
    k_zmlm     <<<4096, 384, 0, stream>>>(x, kw, lg, Ep, QW, lmb, ZT);
    k_wbt      <<<dim3(36, Bb), 256, 0, stream>>>(ZT, Pb, Wsh, WbT);
    k_gemm_nt  <<<1728, 256, 0, stream>>>(lmb, WbT, bias, scalev, out);
}

// Round 15
// 212.386 us; speedup vs baseline: 1.0582x; 1.0582x over previous
//
#include <hip/hip_runtime.h>
#include <hip/hip_bf16.h>
#include <math.h>

// B=64 N=1025 D=384 K=8 R=8 KS=8 H=128 CIN=1152 OUT=384 ; rank m = 2*K*R = 128
static const int Bb = 64, Nn = 1025, Dd = 384, Kk = 8, Rr = 8, Hh = 128, CINc = 1152, OUTo = 384;

// ---- workspace layout (float offsets) ----
#define OFF_PSTAT 0u
#define OFF_RC    475136u
#define OFF_RG    475648u
#define OFF_LG    475712u
#define OFF_SCALE 476288u
#define OFF_N2    505472u
#define OFF_P     505600u
#define OFF_Q     554752u
#define OFF_G     603904u
#define OFF_QW    620288u
#define OFF_PB    669440u
#define OFF_EP    694016u
#define OFF_ZT    3839744u
#define OFF_WBT   5412608u
#define OFF_LM    10131200u

typedef __attribute__((ext_vector_type(8))) short short8;
typedef __attribute__((ext_vector_type(8))) __bf16 bf16x8;
typedef __attribute__((ext_vector_type(4))) float f32x4;

#define MFMA_BF16(a,b,c) __builtin_amdgcn_mfma_f32_16x16x32_bf16( \
    __builtin_bit_cast(bf16x8,(a)), __builtin_bit_cast(bf16x8,(b)), (c), 0, 0, 0)

#define GLDS16(gp, lp) __builtin_amdgcn_global_load_lds( \
    (__attribute__((address_space(1))) void*)(gp), \
    (__attribute__((address_space(3))) void*)(lp), 16, 0, 0)

__device__ __forceinline__ float gelu_t(float v){
    float u = 0.7978845608028654f*(v + 0.044715f*v*v*v);
    return 0.5f*v*(1.0f + tanhf(u));
}
__device__ __forceinline__ float sigm(float v){ return 1.0f/(1.0f+expf(-v)); }
__device__ __forceinline__ unsigned short f2bf(float v){
    return __builtin_bit_cast(unsigned short, __float2bfloat16(v));
}

// ================= A: stats (0..511) | n2 (512..519) | P/Q (520..647) =================
__global__ __launch_bounds__(384) void k_statsprep(const float* __restrict__ x,
    const float* __restrict__ lb, const float* __restrict__ rb,
    float* __restrict__ ps, float* __restrict__ n2,
    float* __restrict__ P, float* __restrict__ Q, unsigned short* __restrict__ Pb){
    int bid = blockIdx.x, t = threadIdx.x;
    if (bid < 512){
        int s = bid & 7, b = bid >> 3;
        int dq = t % 96, ng = t / 96;
        int n0 = s*129, n1 = n0+129 < Nn ? n0+129 : Nn;
        const float4* xb = (const float4*)(x + (size_t)b*Nn*Dd);
        float4 sm = make_float4(0.f,0.f,0.f,0.f), sq = make_float4(0.f,0.f,0.f,0.f);
        for (int n = n0+ng; n < n1; n += 4){
            float4 v = xb[(size_t)n*96 + dq];
            sm.x += v.x; sm.y += v.y; sm.z += v.z; sm.w += v.w;
            sq.x += v.x*v.x; sq.y += v.y*v.y; sq.z += v.z*v.z; sq.w += v.w*v.w;
        }
        __shared__ float4 smS[384];
        __shared__ float4 sqS[384];
        smS[t] = sm; sqS[t] = sq;
        __syncthreads();
        if (t < 96){
            float4 a0 = smS[t], a1 = smS[t+96], a2 = smS[t+192], a3 = smS[t+288];
            float4 q0 = sqS[t], q1 = sqS[t+96], q2 = sqS[t+192], q3 = sqS[t+288];
            float4 a = make_float4(a0.x+a1.x+a2.x+a3.x, a0.y+a1.y+a2.y+a3.y, a0.z+a1.z+a2.z+a3.z, a0.w+a1.w+a2.w+a3.w);
            float4 q = make_float4(q0.x+q1.x+q2.x+q3.x, q0.y+q1.y+q2.y+q3.y, q0.z+q1.z+q2.z+q3.z, q0.w+q1.w+q2.w+q3.w);
            ((float4*)(ps + ((size_t)(b*8+s)*2+0)*Dd))[t] = a;
            ((float4*)(ps + ((size_t)(b*8+s)*2+1)*Dd))[t] = q;
        }
    } else if (bid < 520){
        if (t < 64){
            int k = bid - 512;
            int r = t >> 3, s2 = t & 7;
            const float* L = lb + (size_t)k*Dd*Rr;
            const float* R = rb + (size_t)k*Dd*Rr;
            float a = 0.f, bsum = 0.f, c = 0.f, c2 = 0.f;
            for (int d = 0; d < Dd; ++d){
                float lr = L[d*8+r], ls = L[d*8+s2], rr = R[d*8+r], rs = R[d*8+s2];
                a += lr*ls; bsum += rr*rs; c += lr*rs; c2 += ls*rr;
            }
            float contrib = a*bsum - c*c2;
            for (int m = 32; m > 0; m >>= 1) contrib += __shfl_xor(contrib, m, 64);
            if (t == 0) n2[k] = 2.f*contrib;
        }
    } else {
        int idx = (bid - 520)*384 + t;
        int d = idx >> 7, j = idx & 127;
        int k = (j & 63) >> 3, r = j & 7;
        float lv = lb[((size_t)k*Dd + d)*Rr + r];
        float rv = rb[((size_t)k*Dd + d)*Rr + r];
        float pv = (j < 64) ? lv : rv;
        P[idx] = pv;
        Pb[idx] = f2bf(pv);
        Q[idx] = (j < 64) ? rv : lv;
    }
}

// ================= B: gramqw (0..127) | ctrl (128..191) =================
__global__ __launch_bounds__(512) void k_ctrlgram(const float* __restrict__ x, const float* __restrict__ ps,
    const float* __restrict__ w1, const float* __restrict__ b1,
    const float* __restrict__ w_rot, const float* __restrict__ b_rot,
    const float* __restrict__ w_rg, const float* __restrict__ b_rg,
    const float* __restrict__ w_lg, const float* __restrict__ b_lg,
    const float* __restrict__ w_sc, const float* __restrict__ b_sc,
    const float* __restrict__ sbasis, const float* __restrict__ sstr,
    const float* __restrict__ P, const float* __restrict__ Q, const float* __restrict__ Wsh,
    float* __restrict__ rc, float* __restrict__ rg, float* __restrict__ lg,
    float* __restrict__ scalev, unsigned short* __restrict__ lm,
    float* __restrict__ G, float* __restrict__ QW){
    int bid = blockIdx.x, t = threadIdx.x;
    if (bid < 128){
        __shared__ float qc[384];
        int i = bid;
        for (int d = t; d < Dd; d += 512) qc[d] = Q[d*128 + i];
        __syncthreads();
        if (t < 128){
            float a = 0.f;
            for (int d = 0; d < Dd; ++d) a += qc[d]*P[d*128 + t];
            G[i*128 + t] = a;
        } else {
            int o = t - 128;
            float a = 0.f;
            const float* wrow = Wsh + (size_t)o*Dd;
            for (int d = 0; d < Dd; ++d) a += qc[d]*wrow[d];
            QW[(size_t)i*OUTo + o] = a;
        }
    } else {
        __shared__ float zs[1152];
        __shared__ float hp[4*128];
        __shared__ float hs[128];
        __shared__ float scl[8];
        int b = bid - 128;
        if (t < 384){
            float sm = 0.f, sq = 0.f;
            for (int s = 0; s < 8; ++s){
                sm += ps[((size_t)(b*8+s)*2+0)*Dd + t];
                sq += ps[((size_t)(b*8+s)*2+1)*Dd + t];
            }
            float mean = sm*(1.0f/Nn);
            float var  = sq*(1.0f/Nn) - mean*mean;
            float cls  = x[(size_t)b*Nn*Dd + t];
            zs[t] = cls; zs[Dd + t] = mean; zs[2*Dd + t] = var;
            lm[(size_t)b*Nn*Dd + t] = f2bf(cls);
        }
        __syncthreads();
        {
            int row = t & 127, part = t >> 7;
            const float* wrow = w1 + (size_t)row*CINc + part*288;
            const float* zp = zs + part*288;
            float acc = 0.f;
            for (int c = 0; c < 288; ++c) acc += zp[c]*wrow[c];
            hp[part*128 + row] = acc;
        }
        __syncthreads();
        if (t < 128)
            hs[t] = gelu_t(hp[t] + hp[128+t] + hp[256+t] + hp[384+t] + b1[t]);
        __syncthreads();
        if (t < 8){
            float acc = b_rot[t]; const float* w = w_rot + (size_t)t*Hh;
            for (int c = 0; c < Hh; ++c) acc += hs[c]*w[c];
            rc[b*8+t] = tanhf(acc);
        } else if (t == 8){
            float acc = b_rg[0];
            for (int c = 0; c < Hh; ++c) acc += hs[c]*w_rg[c];
            rg[b] = sigm(acc);
        } else if (t == 9){
            float acc = b_lg[0];
            for (int c = 0; c < Hh; ++c) acc += hs[c]*w_lg[c];
            lg[b] = sigm(acc);
        } else if (t < 18){
            int q = t-10; float acc = b_sc[q]; const float* w = w_sc + (size_t)q*Hh;
            for (int c = 0; c < Hh; ++c) acc += hs[c]*w[c];
            scl[q] = tanhf(acc);
        }
        __syncthreads();
        if (t < 384){
            float acc = 0.f;
            #pragma unroll
            for (int q = 0; q < 8; ++q) acc += scl[q]*sbasis[q*OUTo + t];
            scalev[(size_t)b*OUTo + t] = 1.0f + sstr[0]*tanhf(acc);
        }
    }
}

// ---- fused Cayley/Neumann: X = sum_{k<=2} (DG)^k B0, Ep = rg*(D + X) ----
__global__ __launch_bounds__(512) void k_cayley(const float* __restrict__ G, const float* __restrict__ rc,
                                                const float* __restrict__ n2, const float* __restrict__ rg,
                                                float* __restrict__ Ep){
    __shared__ float GT[128*128];
    __shared__ float Xs[128*128];
    int b = blockIdx.x, t = threadIdx.x;
    for (int lin = t; lin < 16384; lin += 512){
        int i = lin >> 7, m = lin & 127;
        GT[m*128 + i] = G[lin];
    }
    int j0 = (t & 15)*8, i0 = (t >> 4)*4;
    float dj[8], di[4];
    #pragma unroll
    for (int u = 0; u < 8; ++u){
        int j = j0+u; int k = (j&63)>>3;
        float nrm = fmaxf(sqrtf(n2[k]), 1e-6f);
        float al = 0.5f*rc[b*8+k]/nrm;
        dj[u] = (j < 64) ? al : -al;
    }
    #pragma unroll
    for (int u = 0; u < 4; ++u){
        int i = i0+u; int k = (i&63)>>3;
        float nrm = fmaxf(sqrtf(n2[k]), 1e-6f);
        float al = 0.5f*rc[b*8+k]/nrm;
        di[u] = (i < 64) ? al : -al;
    }
    __syncthreads();
    float B0[4][8], acc[4][8];
    #pragma unroll
    for (int ui = 0; ui < 4; ++ui)
        #pragma unroll
        for (int uj = 0; uj < 8; ++uj){
            int i = i0+ui, j = j0+uj;
            float g = GT[j*128 + i];
            B0[ui][uj] = di[ui]*g*dj[uj] + ((i==j) ? di[ui] : 0.f);
        }
    #pragma unroll
    for (int ui = 0; ui < 4; ++ui)
        #pragma unroll
        for (int uj = 0; uj < 8; ++uj)
            Xs[(i0+ui)*128 + j0+uj] = B0[ui][uj];
    __syncthreads();
    for (int pass = 0; pass < 2; ++pass){
        #pragma unroll
        for (int ui = 0; ui < 4; ++ui)
            #pragma unroll
            for (int uj = 0; uj < 8; ++uj) acc[ui][uj] = 0.f;
        for (int m = 0; m < 128; ++m){
            float4 g4 = *(const float4*)&GT[m*128 + i0];
            float4 xa = *(const float4*)&Xs[m*128 + j0];
            float4 xb = *(const float4*)&Xs[m*128 + j0 + 4];
            float gi[4] = {g4.x, g4.y, g4.z, g4.w};
            float xv[8] = {xa.x, xa.y, xa.z, xa.w, xb.x, xb.y, xb.z, xb.w};
            #pragma unroll
            for (int ui = 0; ui < 4; ++ui)
                #pragma unroll
                for (int uj = 0; uj < 8; ++uj)
                    acc[ui][uj] += gi[ui]*xv[uj];
        }
        if (pass == 0){
            __syncthreads();
            #pragma unroll
            for (int ui = 0; ui < 4; ++ui)
                #pragma unroll
                for (int uj = 0; uj < 8; ++uj)
                    Xs[(i0+ui)*128 + j0+uj] = B0[ui][uj] + di[ui]*acc[ui][uj];
            __syncthreads();
        }
    }
    float rgb = rg[b];
    #pragma unroll
    for (int ui = 0; ui < 4; ++ui){
        int i = i0+ui;
        float o[8];
        #pragma unroll
        for (int uj = 0; uj < 8; ++uj){
            int j = j0+uj;
            float x2 = B0[ui][uj] + di[ui]*acc[ui][uj];
            o[uj] = rgb*(x2 + ((i==j) ? di[ui] : 0.f));
        }
        float4* ep4 = (float4*)(Ep + ((size_t)b*128 + i)*128 + j0);
        ep4[0] = make_float4(o[0], o[1], o[2], o[3]);
        ep4[1] = make_float4(o[4], o[5], o[6], o[7]);
    }
}

// ================= D: lm sliding-window (0..2047) | zmatT (2048..4095) — R12-proven =================
__global__ __launch_bounds__(384) void k_zmlm(const float* __restrict__ x, const float* __restrict__ kw,
    const float* __restrict__ lg, const float* __restrict__ Ep, const float* __restrict__ QW,
    unsigned short* __restrict__ lm, unsigned short* __restrict__ ZT){
    __shared__ float shf[3456];
    int bid = blockIdx.x, t = threadIdx.x;
    if (bid < 2048){
        int work = (bid & 7)*256 + (bid >> 3);
        int b = work >> 5, gy = work & 31;
        for (int i = t; i < 3456; i += 384){
            int d = i % 384, tap = i / 384;
            shf[tap*384 + d] = kw[d*9 + tap];
        }
        __syncthreads();
        int dq = t % 96, gxg = t / 96;
        int gx0 = gxg*8;
        float4 kvr[9];
        #pragma unroll
        for (int tap = 0; tap < 9; ++tap)
            kvr[tap] = *(const float4*)(&shf[tap*384 + dq*4]);
        float lgb = lg[b];
        const float4* xb = (const float4*)(x + (size_t)b*Nn*Dd);
        unsigned short* lmb = lm + (size_t)b*Nn*Dd;
        float4 zero4 = make_float4(0.f,0.f,0.f,0.f);
        bool rvalid[3]; int rbase[3];
        #pragma unroll
        for (int rr2 = 0; rr2 < 3; ++rr2){
            int yy = gy + rr2 - 1;
            rvalid[rr2] = (unsigned)yy < 32u;
            rbase[rr2] = 1 + (yy << 5);
        }
        float4 win[3][3];
        #pragma unroll
        for (int rr2 = 0; rr2 < 3; ++rr2){
            win[rr2][0] = zero4;
            if (gx0 > 0 && rvalid[rr2]) win[rr2][0] = xb[(size_t)(rbase[rr2] + gx0-1)*96 + dq];
            win[rr2][1] = rvalid[rr2] ? xb[(size_t)(rbase[rr2] + gx0)*96 + dq] : zero4;
        }
        #pragma unroll
        for (int u = 0; u < 8; ++u){
            int gx = gx0 + u;
            #pragma unroll
            for (int rr2 = 0; rr2 < 3; ++rr2){
                win[rr2][2] = (rvalid[rr2] && gx+1 < 32) ? xb[(size_t)(rbase[rr2] + gx+1)*96 + dq] : zero4;
            }
            float ax = 0.f, ay = 0.f, az = 0.f, aw = 0.f;
            #pragma unroll
            for (int rr2 = 0; rr2 < 3; ++rr2)
                #pragma unroll
                for (int cc = 0; cc < 3; ++cc){
                    float4 xv = win[rr2][cc];
                    float4 kv = kvr[rr2*3+cc];
                    ax += xv.x*kv.x; ay += xv.y*kv.y; az += xv.z*kv.z; aw += xv.w*kv.w;
                }
            float4 xc = win[1][1];
            int n = 1 + (gy << 5) + gx;
            ushort4 o4;
            o4.x = f2bf(xc.x + lgb*(ax - xc.x));
            o4.y = f2bf(xc.y + lgb*(ay - xc.y));
            o4.z = f2bf(xc.z + lgb*(az - xc.z));
            o4.w = f2bf(xc.w + lgb*(aw - xc.w));
            *(ushort4*)(lmb + (size_t)n*Dd + dq*4) = o4;
            #pragma unroll
            for (int rr2 = 0; rr2 < 3; ++rr2){
                win[rr2][0] = win[rr2][1];
                win[rr2][1] = win[rr2][2];
            }
        }
    } else {
        float* Es = shf;
        int z = bid - 2048;
        int ig = z & 31, b = z >> 5;
        int i0 = ig*4;
        for (int lin = t; lin < 512; lin += 384)
            Es[lin] = Ep[((size_t)b*128 + i0 + (lin >> 7))*128 + (lin & 127)];
        __syncthreads();
        float a0=0.f, a1=0.f, a2=0.f, a3=0.f;
        for (int m = 0; m < 128; ++m){
            float qw = QW[(size_t)m*OUTo + t];
            a0 += Es[m]*qw; a1 += Es[128+m]*qw; a2 += Es[256+m]*qw; a3 += Es[384+m]*qw;
        }
        ushort4 uv;
        uv.x = f2bf(a0); uv.y = f2bf(a1); uv.z = f2bf(a2); uv.w = f2bf(a3);
        *(ushort4*)(ZT + ((size_t)b*OUTo + t)*128 + i0) = uv;
    }
}

// ---- WbT[b][o][d] = Wsh[o][d] + sum_m ZT[b][o][m]*P[d][m] (MFMA NT, bf16 out) ----
__global__ __launch_bounds__(256) void k_wbt(const unsigned short* __restrict__ ZT, const unsigned short* __restrict__ Pb,
                                             const float* __restrict__ Wsh, unsigned short* __restrict__ WbT){
    __shared__ short8 As[256];
    __shared__ short8 Bs[256];
    int b = blockIdx.y;
    int mt = blockIdx.x/6, nt2 = blockIdx.x%6;
    int m0 = mt*64, n0 = nt2*64;
    int t = threadIdx.x;
    int w = t>>6, l = t&63;
    int wr = w>>1, wc = w&1;
    const unsigned short* Ab = ZT + (size_t)b*OUTo*128;
    int lrow = t>>2, lseg = t&3;
    f32x4 acc[2][2];
    #pragma unroll
    for (int mi=0;mi<2;++mi)
        #pragma unroll
        for (int ni=0;ni<2;++ni)
            #pragma unroll
            for (int q=0;q<4;++q) acc[mi][ni][q] = 0.f;
    for (int kt = 0; kt < 4; ++kt){
        int k0 = kt*32;
        short8 av = *(const short8*)(Ab + (size_t)(m0+lrow)*128 + k0 + lseg*8);
        short8 bv = *(const short8*)(Pb + (size_t)(n0+lrow)*128 + k0 + lseg*8);
        __syncthreads();
        As[lseg*64 + lrow] = av;
        Bs[lseg*64 + lrow] = bv;
        __syncthreads();
        short8 a0 = As[(l>>4)*64 + wr*32 + (l&15)];
        short8 a1 = As[(l>>4)*64 + wr*32 + 16 + (l&15)];
        short8 b0 = Bs[(l>>4)*64 + wc*32 + (l&15)];
        short8 b1 = Bs[(l>>4)*64 + wc*32 + 16 + (l&15)];
        acc[0][0] = MFMA_BF16(a0, b0, acc[0][0]);
        acc[0][1] = MFMA_BF16(a0, b1, acc[0][1]);
        acc[1][0] = MFMA_BF16(a1, b0, acc[1][0]);
        acc[1][1] = MFMA_BF16(a1, b1, acc[1][1]);
    }
    unsigned short* Wo = WbT + (size_t)b*OUTo*Dd;
    #pragma unroll
    for (int mi=0;mi<2;++mi){
        #pragma unroll
        for (int ni=0;ni<2;++ni){
            int col = n0 + wc*32 + ni*16 + (l&15);
            #pragma unroll
            for (int r=0;r<4;++r){
                int row = m0 + wr*32 + mi*16 + (l>>4)*4 + r;
                float v = Wsh[(size_t)row*Dd + col] + acc[mi][ni][r];
                Wo[(size_t)row*Dd + col] = f2bf(v);
            }
        }
    }
}

// ---- out = (lm_bf16 @ Wb + bias)*scale ; 128x128, BK=32, 4-buf single-barrier depth-2 (proven) ----
__global__ __launch_bounds__(256) void k_gemm_nt(const unsigned short* __restrict__ lm, const unsigned short* __restrict__ WbT,
                                                 const float* __restrict__ bias, const float* __restrict__ scalev,
                                                 float* __restrict__ out){
    __shared__ unsigned short smem[32768];   // 64 KB: 4 bufs x (A 4096 us | B 4096 us)
    __shared__ float svs[128];
    __shared__ float bvs[128];
    int flat = blockIdx.x;                      // 1728
    int work = (flat & 7)*216 + (flat >> 3);    // XCD-chunked (1728 % 8 == 0, bijective)
    int b = work / 27;
    int r = work - b*27;
    int nt = r / 3, ot = r - nt*3;
    int n0 = nt*128, o0 = ot*128;
    int t = threadIdx.x;
    int w = t >> 6, l = t & 63;
    int wr = w >> 1, wc = w & 1;
    const unsigned short* Ab = lm + (size_t)b*Nn*Dd;
    const unsigned short* Bt = WbT + (size_t)b*OUTo*Dd;
    if (t < 128){ svs[t] = scalev[(size_t)b*OUTo + o0 + t]; bvs[t] = bias[o0 + t]; }
    int srow = l >> 2;
    int gch  = (l & 3) ^ ((l >> 3) & 3);
    f32x4 acc[4][4];
    #pragma unroll
    for (int fi = 0; fi < 4; ++fi)
        #pragma unroll
        for (int fj = 0; fj < 4; ++fj)
            #pragma unroll
            for (int q = 0; q < 4; ++q) acc[fi][fj][q] = 0.f;

#define STG(bufi, k0) { \
    unsigned short* Adst = &smem[(bufi)*8192 + (w*32)*32]; \
    unsigned short* Bdst = &smem[(bufi)*8192 + 4096 + (w*32)*32]; \
    GLDS16(Ab + (size_t)(n0 + w*32 + srow)*Dd + (k0) + gch*8, Adst); \
    GLDS16(Ab + (size_t)(n0 + w*32 + 16 + srow)*Dd + (k0) + gch*8, Adst + 512); \
    GLDS16(Bt + (size_t)(o0 + w*32 + srow)*Dd + (k0) + gch*8, Bdst); \
    GLDS16(Bt + (size_t)(o0 + w*32 + 16 + srow)*Dd + (k0) + gch*8, Bdst + 512); }

    STG(0, 0);
    STG(1, 32);
    int rch = ((l>>4) ^ (((l&15)>>1)&3)) * 8;
    int raBase = (wr*64 + (l&15))*32;
    int rbBase = (wc*64 + (l&15))*32;
    for (int kt = 0; kt < 12; ++kt){
        if (kt < 10) STG((kt+2)&3, (kt+2)*32);
        if (kt < 10)       asm volatile("s_waitcnt vmcnt(8)" ::: "memory");
        else if (kt == 10) asm volatile("s_waitcnt vmcnt(4)" ::: "memory");
        else               asm volatile("s_waitcnt vmcnt(0)" ::: "memory");
        __builtin_amdgcn_s_barrier();        // AFTER own-vmcnt: cross-wave staged data visible
        __builtin_amdgcn_sched_barrier(0);
        const unsigned short* As  = &smem[(kt&3)*8192];
        const unsigned short* Bs2 = &smem[(kt&3)*8192 + 4096];
        short8 a[4], bb[4];
        #pragma unroll
        for (int f = 0; f < 4; ++f){
            a[f]  = *(const short8*)&As [raBase + f*512 + rch];
            bb[f] = *(const short8*)&Bs2[rbBase + f*512 + rch];
        }
        #pragma unroll
        for (int fi = 0; fi < 4; ++fi)
            #pragma unroll
            for (int fj = 0; fj < 4; ++fj)
                acc[fi][fj] = MFMA_BF16(a[fi], bb[fj], acc[fi][fj]);
    }
#undef STG
    float* Cs = (float*)smem;            // [64][132] f32
    #pragma unroll
    for (int h = 0; h < 2; ++h){
        __syncthreads();
        if (wr == h){
            #pragma unroll
            for (int fi = 0; fi < 4; ++fi)
                #pragma unroll
                for (int fj = 0; fj < 4; ++fj){
                    int col = wc*64 + fj*16 + (l&15);
                    #pragma unroll
                    for (int q = 0; q < 4; ++q){
                        int row = fi*16 + (l>>4)*4 + q;
                        Cs[row*132 + col] = acc[fi][fj][q];
                    }
                }
        }
        __syncthreads();
        #pragma unroll
        for (int p = 0; p < 8; ++p){
            int idx = p*256 + t;
            int row = idx >> 5, c4 = idx & 31;
            int gr = n0 + h*64 + row;
            if (gr < Nn){
                float4 v = *(const float4*)&Cs[row*132 + c4*4];
                float4 o4;
                o4.x = svs[c4*4+0]*(bvs[c4*4+0] + v.x);
                o4.y = svs[c4*4+1]*(bvs[c4*4+1] + v.y);
                o4.z = svs[c4*4+2]*(bvs[c4*4+2] + v.z);
                o4.w = svs[c4*4+3]*(bvs[c4*4+3] + v.w);
                *(float4*)(out + ((size_t)b*Nn + gr)*OUTo + o0 + c4*4) = o4;
            }
        }
    }
}

extern "C" void kernel_launch(void* const* d_in, const int* in_sizes, int n_in,
                              void* d_out, int out_size, void* d_ws, size_t ws_size,
                              hipStream_t stream){
    const float* x     = (const float*)d_in[0];
    const float* Wsh   = (const float*)d_in[1];
    const float* bias  = (const float*)d_in[2];
    const float* lb    = (const float*)d_in[3];
    const float* rb    = (const float*)d_in[4];
    const float* sbasis= (const float*)d_in[5];
    const float* sstr  = (const float*)d_in[6];
    const float* kw    = (const float*)d_in[7];
    const float* w1    = (const float*)d_in[8];
    const float* b1    = (const float*)d_in[9];
    const float* w_rot = (const float*)d_in[10];
    const float* b_rot = (const float*)d_in[11];
    const float* w_rg  = (const float*)d_in[12];
    const float* b_rg  = (const float*)d_in[13];
    const float* w_lg  = (const float*)d_in[14];
    const float* b_lg  = (const float*)d_in[15];
    const float* w_sc  = (const float*)d_in[16];
    const float* b_sc  = (const float*)d_in[17];
    float* out = (float*)d_out;
    float* ws  = (float*)d_ws;

    float* ps     = ws + OFF_PSTAT;
    float* rc     = ws + OFF_RC;
    float* rg     = ws + OFF_RG;
    float* lg     = ws + OFF_LG;
    float* scalev = ws + OFF_SCALE;
    float* n2     = ws + OFF_N2;
    float* P      = ws + OFF_P;
    float* Q      = ws + OFF_Q;
    float* G      = ws + OFF_G;
    float* QW     = ws + OFF_QW;
    unsigned short* Pb  = (unsigned short*)(ws + OFF_PB);
    float* Ep     = ws + OFF_EP;
    unsigned short* ZT  = (unsigned short*)(ws + OFF_ZT);
    unsigned short* WbT = (unsigned short*)(ws + OFF_WBT);
    unsigned short* lmb = (unsigned short*)(ws + OFF_LM);

    k_statsprep<<<648, 384, 0, stream>>>(x, lb, rb, ps, n2, P, Q, Pb);
    k_ctrlgram <<<192, 512, 0, stream>>>(x, ps, w1, b1, w_rot, b_rot, w_rg, b_rg, w_lg, b_lg,
                                         w_sc, b_sc, sbasis, sstr, P, Q, Wsh,
                                         rc, rg, lg, scalev, lmb, G, QW);
    k_cayley   <<<Bb, 512, 0, stream>>>(G, rc, n2, rg, Ep);
    k_zmlm     <<<4096, 384, 0, stream>>>(x, kw, lg, Ep, QW, lmb, ZT);
    k_wbt      <<<dim3(36, Bb), 256, 0, stream>>>(ZT, Pb, Wsh, WbT);
    k_gemm_nt  <<<1728, 256, 0, stream>>>(lmb, WbT, bias, scalev, out);
}